// Round 11
// baseline (221.827 us; speedup 1.0000x reference)
//
#include <hip/hip_runtime.h>
#include <math.h>

#define B_ 8
#define CIN_ 512
#define K_ 64
#define V_ 256
#define T_ 1024
#define KS_ 23
#define EPS_ 1e-5f
#define NTC_ 16   // lambda t-chunks (partials)

typedef __attribute__((ext_vector_type(8))) short bf16x8;
typedef __attribute__((ext_vector_type(4))) float f32x4;

__device__ __forceinline__ unsigned short f2bf(float f) {
    union { float f; unsigned u; } x; x.f = f;
    unsigned r = x.u + 0x7fffu + ((x.u >> 16) & 1u);   // RNE
    return (unsigned short)(r >> 16);
}
__device__ __forceinline__ float bf2f(unsigned short h) {
    union { unsigned u; float f; } x; x.u = ((unsigned)h) << 16;
    return x.f;
}

// ---------------------------------------------------------------------------
// prep: merged cvtT (blocks 0..2047) + prew (blocks 2048..2239).
// Block 2048 zeroes stat[640] + completion counters (32 ints).
// ---------------------------------------------------------------------------
__global__ __launch_bounds__(256) void prep_kernel(
    const float* __restrict__ x, const float* __restrict__ ctx,
    const float* __restrict__ Wq, const float* __restrict__ Wk,
    const float* __restrict__ Wv,
    unsigned short* __restrict__ xT, unsigned short* __restrict__ cT,
    unsigned short* __restrict__ Wb, float* __restrict__ stat)
{
    __shared__ unsigned short sh[64][72];
    const int tid = threadIdx.x;
    const int id = blockIdx.x;
    if (id < 2048) {
        const int t0 = (id & 15) * 64, c0 = ((id >> 4) & 7) * 64;
        const int z = id >> 7, b = z & 7, which = z >> 3;
        const float* src = which ? ctx : x;
        unsigned short* dst = which ? cT : xT;
        const int cl = tid >> 2, qq = tid & 3;
        const float* row = src + ((size_t)b * CIN_ + c0 + cl) * T_ + t0 + qq * 16;
        #pragma unroll
        for (int u = 0; u < 4; u++) {
            float4 f = *(const float4*)(row + 4 * u);
            sh[qq * 16 + 4 * u + 0][cl] = f2bf(f.x);
            sh[qq * 16 + 4 * u + 1][cl] = f2bf(f.y);
            sh[qq * 16 + 4 * u + 2][cl] = f2bf(f.z);
            sh[qq * 16 + 4 * u + 3][cl] = f2bf(f.w);
        }
        __syncthreads();
        const int tl = tid >> 2;
        unsigned short* orow = dst + ((size_t)b * T_ + t0 + tl) * CIN_ + c0 + qq * 16;
        *(bf16x8*)(orow)     = *(bf16x8*)&sh[tl][qq * 16];
        *(bf16x8*)(orow + 8) = *(bf16x8*)&sh[tl][qq * 16 + 8];
    } else {
        const int wid = id - 2048;
        if (wid == 0 && tid < 168)   // stat 640 f + 32 int counters
            ((float4*)stat)[tid] = make_float4(0.f, 0.f, 0.f, 0.f);
        const int i4 = wid * 256 + tid;
        const int n1 = K_ * CIN_ / 4, n2 = 2 * K_ * CIN_ / 4;
        const float* src; int off;
        if (i4 < n1)      { src = Wq; off = i4; }
        else if (i4 < n2) { src = Wk; off = i4 - n1; }
        else              { src = Wv; off = i4 - n2; }
        float4 f = ((const float4*)src)[off];
        ushort4 h;
        h.x = f2bf(f.x); h.y = f2bf(f.y); h.z = f2bf(f.z); h.w = f2bf(f.w);
        *(ushort4*)(Wb + (size_t)i4 * 4) = h;
    }
}

// ---------------------------------------------------------------------------
// proj_mfma5: bf16 MFMA projection.  k and v now stored as bf16 (half the
// write traffic); BN stats and softmax partials computed from fp32 registers.
// yb==0: q->qT+stats.  yb==1: k->k_bufh bf16 + kml.  yb>=2: v->v_rawh + stats.
// ---------------------------------------------------------------------------
__global__ __launch_bounds__(256) void proj_mfma5(
    const unsigned short* __restrict__ xT, const unsigned short* __restrict__ cT,
    const unsigned short* __restrict__ Wb,
    const float* __restrict__ bq, const float* __restrict__ bk,
    const float* __restrict__ bv,
    unsigned short* __restrict__ k_bufh, unsigned short* __restrict__ v_rawh,
    unsigned short* __restrict__ qT, float* __restrict__ stat,
    float* __restrict__ kml)
{
    __shared__ unsigned short Wt[64][72];
    __shared__ unsigned short Xt[128][72];
    const int tid = threadIdx.x;
    const int b = blockIdx.z, t0 = blockIdx.x * 128, yb = blockIdx.y;

    const unsigned short* in; const unsigned short* W; const float* bias;
    unsigned short* outp = nullptr; int ch0 = 0;
    float* ssum = nullptr; float* ssq = nullptr;
    if (yb == 0)      { in = xT; W = Wb;             bias = bq;
                        ssum = stat; ssq = stat + 64; ch0 = 0; }
    else if (yb == 1) { in = cT; W = Wb + K_ * CIN_; bias = bk;
                        outp = k_bufh + (size_t)b * K_ * T_; }
    else { int m0 = (yb - 2) * 64; in = cT;
           W = Wb + 2 * K_ * CIN_ + (size_t)m0 * CIN_; bias = bv + m0;
           outp = v_rawh + ((size_t)b * V_ + m0) * T_;
           ssum = stat + 128; ssq = stat + 384; ch0 = m0; }

    const int lane = tid & 63, w = tid >> 6;
    const int col = lane & 15, quad = lane >> 4;
    const int wm = tid >> 2, wp = tid & 3;
    const int xt = tid >> 1, xh = tid & 1;

    f32x4 acc[8];
    #pragma unroll
    for (int j = 0; j < 8; j++) acc[j] = (f32x4){0.f, 0.f, 0.f, 0.f};

    for (int c0 = 0; c0 < CIN_; c0 += 64) {
        {
            const unsigned short* ws = W + (size_t)wm * CIN_ + c0 + wp * 16;
            *(bf16x8*)&Wt[wm][wp * 16]     = *(const bf16x8*)(ws);
            *(bf16x8*)&Wt[wm][wp * 16 + 8] = *(const bf16x8*)(ws + 8);
            const unsigned short* xs = in + ((size_t)b * T_ + t0 + xt) * CIN_ + c0 + xh * 32;
            #pragma unroll
            for (int u = 0; u < 4; u++)
                *(bf16x8*)&Xt[xt][xh * 32 + 8 * u] = *(const bf16x8*)(xs + 8 * u);
        }
        __syncthreads();
        #pragma unroll
        for (int ks = 0; ks < 2; ks++) {
            const int kc = ks * 32 + quad * 8;
            bf16x8 af = *(bf16x8*)&Wt[w * 16 + col][kc];
            #pragma unroll
            for (int j = 0; j < 8; j++) {
                bf16x8 bfr = *(bf16x8*)&Xt[j * 16 + col][kc];
                acc[j] = __builtin_amdgcn_mfma_f32_16x16x32_bf16(af, bfr, acc[j], 0, 0, 0);
            }
        }
        __syncthreads();
    }

    float bias_v[4], s[4], sq[4], mr[4], lr[4];
    #pragma unroll
    for (int r = 0; r < 4; r++) {
        bias_v[r] = bias[w * 16 + quad * 4 + r];
        s[r] = 0.f; sq[r] = 0.f; mr[r] = -1e30f; lr[r] = 0.f;
    }
    #pragma unroll
    for (int j = 0; j < 8; j++) {
        float o[4];
        #pragma unroll
        for (int r = 0; r < 4; r++) {
            o[r] = acc[j][r] + bias_v[r];
            s[r] += o[r]; sq[r] += o[r] * o[r];
        }
        if (yb == 0) {
            ushort4 h;
            h.x = f2bf(o[0]); h.y = f2bf(o[1]); h.z = f2bf(o[2]); h.w = f2bf(o[3]);
            *(ushort4*)(qT + ((size_t)b * T_ + t0 + j * 16 + col) * K_ + w * 16 + quad * 4) = h;
        } else {
            #pragma unroll
            for (int r = 0; r < 4; r++)
                outp[(size_t)(w * 16 + quad * 4 + r) * T_ + t0 + j * 16 + col] = f2bf(o[r]);
            if (yb == 1) {
                #pragma unroll
                for (int r = 0; r < 4; r++) {
                    float mn = fmaxf(mr[r], o[r]);
                    lr[r] = lr[r] * __expf(mr[r] - mn) + __expf(o[r] - mn);
                    mr[r] = mn;
                }
            }
        }
    }
    if (yb == 1) {
        #pragma unroll
        for (int r = 0; r < 4; r++) {
            float m = mr[r], l = lr[r];
            #pragma unroll
            for (int off = 1; off < 16; off <<= 1) {
                float mo = __shfl_xor(m, off, 64);
                float lo = __shfl_xor(l, off, 64);
                float mn = fmaxf(m, mo);
                l = l * __expf(m - mn) + lo * __expf(mo - mn);
                m = mn;
            }
            if (col == 0) {
                int row = w * 16 + quad * 4 + r;
                float* p = kml + (((size_t)b * K_ + row) * 8 + (t0 >> 7)) * 2;
                p[0] = m; p[1] = l;
            }
        }
    } else {
        #pragma unroll
        for (int r = 0; r < 4; r++) {
            float sv = s[r], qv = sq[r];
            #pragma unroll
            for (int off = 1; off < 16; off <<= 1) {
                sv += __shfl_xor(sv, off, 64);
                qv += __shfl_xor(qv, off, 64);
            }
            if (col == 0) {
                int ch = ch0 + w * 16 + quad * 4 + r;
                atomicAdd(&ssum[ch], sv);
                atomicAdd(&ssq[ch], qv);
            }
        }
    }
}

// ---------------------------------------------------------------------------
// lambda5: softmax-normalized lambda partials from bf16 k/v + split-K-style
// tail reduction.  512 blocks; the LAST block of each (b,v0) group (device
// atomic counter) sums the 16 clp partials and emits clb2/hterm (prep_cl
// fused away).  Fence-release before counter, fence-acquire before re-read.
// ---------------------------------------------------------------------------
__global__ __launch_bounds__(256) void lambda_kernel5(
    const unsigned short* __restrict__ k_bufh, const unsigned short* __restrict__ v_rawh,
    const float* __restrict__ kml, float* __restrict__ clp,
    const float* __restrict__ stat,
    const float* __restrict__ gq, const float* __restrict__ betaq,
    const float* __restrict__ gv, const float* __restrict__ betav,
    unsigned short* __restrict__ clb2, float* __restrict__ hterm,
    int* __restrict__ cnt)
{
    __shared__ __align__(16) float nks[K_][68];
    __shared__ __align__(16) float vls[64][68];
    __shared__ float mrow[64], lrow[64];
    __shared__ int lastdone;
    const int tid = threadIdx.x;
    const int b = blockIdx.z, v0 = blockIdx.y * 64, tc = blockIdx.x, t0 = tc * 64;

    if (tid < 64) {
        const float2* p = (const float2*)(kml + ((size_t)b * K_ + tid) * 16);
        float m = -1e30f, l = 0.f;
        #pragma unroll
        for (int sgi = 0; sgi < 8; sgi++) {
            float2 ml = p[sgi];
            float mn = fmaxf(m, ml.x);
            l = l * __expf(m - mn) + ml.y * __expf(ml.x - mn);
            m = mn;
        }
        mrow[tid] = m; lrow[tid] = 1.f / l;
    }
    __syncthreads();
    {
        const int r = tid >> 2, q = tid & 3;
        const unsigned short* nrow = k_bufh + ((size_t)b * K_ + r) * T_ + t0 + q * 16;
        const unsigned short* vrow = v_rawh + ((size_t)b * V_ + v0 + r) * T_ + t0 + q * 16;
        const float mr = mrow[r], li = lrow[r];
        bf16x8 ka = *(const bf16x8*)(nrow);
        bf16x8 kb = *(const bf16x8*)(nrow + 8);
        bf16x8 va = *(const bf16x8*)(vrow);
        bf16x8 vb = *(const bf16x8*)(vrow + 8);
        #pragma unroll
        for (int i = 0; i < 8; i++) {
            nks[r][q * 16 + i]     = __expf(bf2f((unsigned short)ka[i]) - mr) * li;
            nks[r][q * 16 + 8 + i] = __expf(bf2f((unsigned short)kb[i]) - mr) * li;
            vls[q * 16 + i][r]     = bf2f((unsigned short)va[i]);
            vls[q * 16 + 8 + i][r] = bf2f((unsigned short)vb[i]);
        }
    }
    __syncthreads();
    const int tv = tid & 15, tk = tid >> 4;
    float4 acc[4];
    #pragma unroll
    for (int i = 0; i < 4; i++) acc[i] = make_float4(0.f, 0.f, 0.f, 0.f);
    for (int tt = 0; tt < 16; tt++) {
        float4 w0 = *(float4*)&vls[4 * tt + 0][4 * tv];
        float4 w1 = *(float4*)&vls[4 * tt + 1][4 * tv];
        float4 w2 = *(float4*)&vls[4 * tt + 2][4 * tv];
        float4 w3 = *(float4*)&vls[4 * tt + 3][4 * tv];
        #pragma unroll
        for (int i = 0; i < 4; i++) {
            float4 n = *(float4*)&nks[4 * tk + i][4 * tt];
            acc[i] += w0 * n.x + w1 * n.y + w2 * n.z + w3 * n.w;
        }
    }
    #pragma unroll
    for (int i = 0; i < 4; i++)
        *(float4*)&clp[(((size_t)b * NTC_ + tc) * K_ + 4 * tk + i) * V_ + v0 + 4 * tv] = acc[i];

    // ---- completion counter: last block of (b,v0) group does the tail ----
    __threadfence();
    __syncthreads();
    if (tid == 0) {
        int old = atomicAdd(&cnt[b * 4 + (v0 >> 6)], 1);
        lastdone = (old == NTC_ - 1);
    }
    __syncthreads();
    if (!lastdone) return;
    __threadfence();   // acquire: make other blocks' clp stores visible

    __shared__ float qsc[64], qsh[64], red[4][64];
    const float inv_n = 1.f / (B_ * T_);
    if (tid < 64) {
        float mean = stat[tid] * inv_n;
        float var  = stat[64 + tid] * inv_n - mean * mean;
        float sc = gq[tid] * rsqrtf(var + EPS_);
        qsc[tid] = sc; qsh[tid] = betaq[tid] - mean * sc;
    }
    const int vl = tid & 63, kq = tid >> 6;
    const int c = v0 + vl;
    float vmean = stat[128 + c] * inv_n;
    float vvar  = stat[384 + c] * inv_n - vmean * vmean;
    float vsv = gv[c] * rsqrtf(vvar + EPS_);
    float vhv = betav[c] - vmean * vsv;
    __syncthreads();
    float h = 0.f;
    for (int kk = 0; kk < 16; kk++) {
        int k = kq * 16 + kk;
        float a = 0.f;
        #pragma unroll
        for (int t2 = 0; t2 < NTC_; t2++)
            a += clp[(((size_t)b * NTC_ + t2) * K_ + k) * V_ + c];
        float clbv = a * vsv + vhv;
        h += qsh[k] * clbv;
        clb2[((size_t)b * V_ + c) * K_ + k] = f2bf(clbv * qsc[k]);
    }
    red[kq][vl] = h;
    __syncthreads();
    if (tid < 64)
        hterm[(size_t)b * V_ + v0 + tid] =
            red[0][tid] + red[1][tid] + red[2][tid] + red[3][tid];
}

// ---------------------------------------------------------------------------
// out5: fused qp + content-MFMA + conv epilogue; v window now read as bf16.
// ---------------------------------------------------------------------------
__global__ __launch_bounds__(256) void out_kernel5(
    const unsigned short* __restrict__ qT, const unsigned short* __restrict__ clb2,
    const float* __restrict__ hterm, const unsigned short* __restrict__ v_rawh,
    const float* __restrict__ stat,
    const float* __restrict__ gq, const float* __restrict__ betaq,
    const float* __restrict__ gv, const float* __restrict__ betav,
    const float* __restrict__ pos_w, const float* __restrict__ pos_b,
    float* __restrict__ out)
{
    __shared__ unsigned short qTt[64][72];
    __shared__ unsigned short clv[64][72];
    __shared__ float vs2T[88][68];
    __shared__ float qpt[64][24];
    __shared__ float pws[64][24];
    __shared__ float qsc[64], qsh[64];
    __shared__ float consts[24];
    __shared__ float hvs[64];
    const int tid = threadIdx.x;
    const int b = blockIdx.z, v0 = blockIdx.y * 64, t0 = blockIdx.x * 64;
    const float inv_n = 1.f / (B_ * T_);

    if (tid < 64) {
        float mean = stat[tid] * inv_n;
        float var  = stat[64 + tid] * inv_n - mean * mean;
        float sc = gq[tid] * rsqrtf(var + EPS_);
        qsc[tid] = sc; qsh[tid] = betaq[tid] - mean * sc;
        hvs[tid] = hterm[(size_t)b * V_ + v0 + tid];
    }
    {
        const int rl = tid >> 2, part = tid & 3;
        const unsigned short* qs = qT + ((size_t)b * T_ + t0 + rl) * K_ + part * 16;
        *(bf16x8*)&qTt[rl][part * 16]     = *(const bf16x8*)(qs);
        *(bf16x8*)&qTt[rl][part * 16 + 8] = *(const bf16x8*)(qs + 8);
        const unsigned short* cs = clb2 + ((size_t)b * V_ + v0 + rl) * K_ + part * 16;
        *(bf16x8*)&clv[rl][part * 16]     = *(const bf16x8*)(cs);
        *(bf16x8*)&clv[rl][part * 16 + 8] = *(const bf16x8*)(cs + 8);
    }
    {
        const int vl = tid >> 2, qq = tid & 3;
        const int c = v0 + vl;
        float vmean = stat[128 + c] * inv_n;
        float vvar  = stat[384 + c] * inv_n - vmean * vmean;
        float vsv = gv[c] * rsqrtf(vvar + EPS_);
        float vhv = betav[c] - vmean * vsv;
        const unsigned short* vrow = v_rawh + ((size_t)b * V_ + c) * T_;
        #pragma unroll
        for (int i = 0; i < 22; i++) {
            int cc = qq + 4 * i;
            if (cc < 86) {
                int t = t0 + cc - 11;
                vs2T[cc][vl] = (t >= 0 && t < T_) ? bf2f(vrow[t]) * vsv + vhv : 0.f;
            }
        }
    }
    __syncthreads();

    for (int idx = tid; idx < K_ * 24; idx += 256) {
        int k = idx / 24, s = idx % 24;
        pws[k][s] = qsc[k] * (s < KS_ ? pos_w[k * KS_ + s] : pos_b[k]);
    }
    if (tid < 24) {
        float cs = 0.f;
        for (int k = 0; k < K_; k++)
            cs += qsh[k] * (tid < KS_ ? pos_w[k * KS_ + tid] : pos_b[k]);
        consts[tid] = cs;
    }
    __syncthreads();

    {
        const int t = tid >> 2, sg = tid & 3, s0 = sg * 6;
        float a[6];
        #pragma unroll
        for (int u = 0; u < 6; u++) a[u] = consts[s0 + u];
        #pragma unroll
        for (int kb = 0; kb < 8; kb++) {
            bf16x8 qv = *(bf16x8*)&qTt[t][kb * 8];
            #pragma unroll
            for (int j = 0; j < 8; j++) {
                float q = bf2f((unsigned short)qv[j]);
                #pragma unroll
                for (int u = 0; u < 6; u++) a[u] += q * pws[kb * 8 + j][s0 + u];
            }
        }
        #pragma unroll
        for (int u = 0; u < 6; u++) qpt[t][s0 + u] = a[u];
    }
    __syncthreads();

    const int lane = tid & 63, w = tid >> 6;
    const int col = lane & 15, quad = lane >> 4;

    f32x4 acc[4];
    #pragma unroll
    for (int tf = 0; tf < 4; tf++) acc[tf] = (f32x4){0.f, 0.f, 0.f, 0.f};

    #pragma unroll
    for (int ks = 0; ks < 2; ks++) {
        const int kc = ks * 32 + quad * 8;
        bf16x8 af = *(bf16x8*)&clv[w * 16 + col][kc];
        #pragma unroll
        for (int tf = 0; tf < 4; tf++) {
            bf16x8 bq = *(bf16x8*)&qTt[tf * 16 + col][kc];
            acc[tf] = __builtin_amdgcn_mfma_f32_16x16x32_bf16(af, bq, acc[tf], 0, 0, 0);
        }
    }

    const int vb = w * 16 + quad * 4;
    float4 hv4 = *(float4*)&hvs[vb];
    #pragma unroll
    for (int tf = 0; tf < 4; tf++) {
        const int lt = tf * 16 + col;
        float qv[24];
        #pragma unroll
        for (int u = 0; u < 6; u++)
            *(float4*)&qv[4 * u] = *(float4*)&qpt[lt][4 * u];
        float4 a; a.x = acc[tf][0]; a.y = acc[tf][1]; a.z = acc[tf][2]; a.w = acc[tf][3];
        #pragma unroll
        for (int s = 0; s < KS_; s++) {
            float4 wv = *(float4*)&vs2T[lt + s][vb];
            a.x += qv[s] * wv.x; a.y += qv[s] * wv.y;
            a.z += qv[s] * wv.z; a.w += qv[s] * wv.w;
        }
        float base = qv[23];
        a.x += base + hv4.x; a.y += base + hv4.y;
        a.z += base + hv4.z; a.w += base + hv4.w;
        float* ap = (float*)&a;
        #pragma unroll
        for (int r = 0; r < 4; r++)
            out[((size_t)b * V_ + v0 + vb + r) * T_ + t0 + lt] = ap[r];
    }
}

extern "C" void kernel_launch(void* const* d_in, const int* in_sizes, int n_in,
                              void* d_out, int out_size, void* d_ws, size_t ws_size,
                              hipStream_t stream)
{
    const float* x     = (const float*)d_in[0];
    const float* ctx   = (const float*)d_in[1];
    const float* Wq    = (const float*)d_in[2];
    const float* bq    = (const float*)d_in[3];
    const float* Wk    = (const float*)d_in[4];
    const float* bk    = (const float*)d_in[5];
    const float* Wv    = (const float*)d_in[6];
    const float* bv    = (const float*)d_in[7];
    const float* gq    = (const float*)d_in[8];
    const float* betaq = (const float*)d_in[9];
    const float* gv    = (const float*)d_in[10];
    const float* betav = (const float*)d_in[11];
    const float* pos_w = (const float*)d_in[12];
    const float* pos_b = (const float*)d_in[13];
    float* out = (float*)d_out;

    float* ws    = (float*)d_ws;
    float* clp   = ws;                                   // B*NTC*K*V = 2097152 f
    float* stat  = clp + (size_t)B_ * NTC_ * K_ * V_;    // 640 f + 32 int
    int*   cnt   = (int*)(stat + 640);
    float* hterm = stat + 672;                           // B*V = 2048
    float* kml   = hterm + (size_t)B_ * V_;              // B*K*16 = 8192
    unsigned short* k_bufh = (unsigned short*)(kml + (size_t)B_ * K_ * 16);  // B*K*T
    unsigned short* v_rawh = k_bufh + (size_t)B_ * K_ * T_;                  // B*V*T
    unsigned short* xT     = v_rawh + (size_t)B_ * V_ * T_;
    unsigned short* cT     = xT + (size_t)B_ * T_ * CIN_;
    unsigned short* Wb     = cT + (size_t)B_ * T_ * CIN_;
    unsigned short* qT     = Wb + (size_t)(2 * K_ + V_) * CIN_;
    unsigned short* clb2   = qT + (size_t)B_ * T_ * K_;

    prep_kernel<<<dim3(2048 + 192), 256, 0, stream>>>(
        x, ctx, Wq, Wk, Wv, xT, cT, Wb, stat);
    proj_mfma5<<<dim3(T_ / 128, 6, B_), 256, 0, stream>>>(
        xT, cT, Wb, bq, bk, bv, k_bufh, v_rawh, qT, stat, kml);
    lambda_kernel5<<<dim3(NTC_, V_ / 64, B_), 256, 0, stream>>>(
        k_bufh, v_rawh, kml, clp, stat, gq, betaq, gv, betav, clb2, hterm, cnt);
    out_kernel5<<<dim3(T_ / 64, V_ / 64, B_), 256, 0, stream>>>(
        qT, clb2, hterm, v_rawh, stat, gq, betaq, gv, betav, pos_w, pos_b, out);
}

// Round 12
// 158.189 us; speedup vs baseline: 1.4023x; 1.4023x over previous
//
#include <hip/hip_runtime.h>
#include <math.h>

#define B_ 8
#define CIN_ 512
#define K_ 64
#define V_ 256
#define T_ 1024
#define KS_ 23
#define EPS_ 1e-5f
#define NTC_ 16   // lambda t-chunks (partials)

typedef __attribute__((ext_vector_type(8))) short bf16x8;
typedef __attribute__((ext_vector_type(4))) float f32x4;

__device__ __forceinline__ unsigned short f2bf(float f) {
    union { float f; unsigned u; } x; x.f = f;
    unsigned r = x.u + 0x7fffu + ((x.u >> 16) & 1u);   // RNE
    return (unsigned short)(r >> 16);
}
__device__ __forceinline__ float bf2f(unsigned short h) {
    union { unsigned u; float f; } x; x.u = ((unsigned)h) << 16;
    return x.f;
}

// ---------------------------------------------------------------------------
// prep: merged cvtT (blocks 0..2047) + prew (blocks 2048..2239).
// Block 2048 zeroes stat[640].
// ---------------------------------------------------------------------------
__global__ __launch_bounds__(256) void prep_kernel(
    const float* __restrict__ x, const float* __restrict__ ctx,
    const float* __restrict__ Wq, const float* __restrict__ Wk,
    const float* __restrict__ Wv,
    unsigned short* __restrict__ xT, unsigned short* __restrict__ cT,
    unsigned short* __restrict__ Wb, float* __restrict__ stat)
{
    __shared__ unsigned short sh[64][72];
    const int tid = threadIdx.x;
    const int id = blockIdx.x;
    if (id < 2048) {
        const int t0 = (id & 15) * 64, c0 = ((id >> 4) & 7) * 64;
        const int z = id >> 7, b = z & 7, which = z >> 3;
        const float* src = which ? ctx : x;
        unsigned short* dst = which ? cT : xT;
        const int cl = tid >> 2, qq = tid & 3;
        const float* row = src + ((size_t)b * CIN_ + c0 + cl) * T_ + t0 + qq * 16;
        #pragma unroll
        for (int u = 0; u < 4; u++) {
            float4 f = *(const float4*)(row + 4 * u);
            sh[qq * 16 + 4 * u + 0][cl] = f2bf(f.x);
            sh[qq * 16 + 4 * u + 1][cl] = f2bf(f.y);
            sh[qq * 16 + 4 * u + 2][cl] = f2bf(f.z);
            sh[qq * 16 + 4 * u + 3][cl] = f2bf(f.w);
        }
        __syncthreads();
        const int tl = tid >> 2;
        unsigned short* orow = dst + ((size_t)b * T_ + t0 + tl) * CIN_ + c0 + qq * 16;
        *(bf16x8*)(orow)     = *(bf16x8*)&sh[tl][qq * 16];
        *(bf16x8*)(orow + 8) = *(bf16x8*)&sh[tl][qq * 16 + 8];
    } else {
        const int wid = id - 2048;
        if (wid == 0 && tid < 160)
            ((float4*)stat)[tid] = make_float4(0.f, 0.f, 0.f, 0.f);
        const int i4 = wid * 256 + tid;
        const int n1 = K_ * CIN_ / 4, n2 = 2 * K_ * CIN_ / 4;
        const float* src; int off;
        if (i4 < n1)      { src = Wq; off = i4; }
        else if (i4 < n2) { src = Wk; off = i4 - n1; }
        else              { src = Wv; off = i4 - n2; }
        float4 f = ((const float4*)src)[off];
        ushort4 h;
        h.x = f2bf(f.x); h.y = f2bf(f.y); h.z = f2bf(f.z); h.w = f2bf(f.w);
        *(ushort4*)(Wb + (size_t)i4 * 4) = h;
    }
}

// ---------------------------------------------------------------------------
// proj_mfma5: bf16 MFMA projection; k/v stored bf16; BN stats + per-128t
// online-softmax partials computed from fp32 registers in the epilogue.
// ---------------------------------------------------------------------------
__global__ __launch_bounds__(256) void proj_mfma5(
    const unsigned short* __restrict__ xT, const unsigned short* __restrict__ cT,
    const unsigned short* __restrict__ Wb,
    const float* __restrict__ bq, const float* __restrict__ bk,
    const float* __restrict__ bv,
    unsigned short* __restrict__ k_bufh, unsigned short* __restrict__ v_rawh,
    unsigned short* __restrict__ qT, float* __restrict__ stat,
    float* __restrict__ kml)
{
    __shared__ unsigned short Wt[64][72];
    __shared__ unsigned short Xt[128][72];
    const int tid = threadIdx.x;
    const int b = blockIdx.z, t0 = blockIdx.x * 128, yb = blockIdx.y;

    const unsigned short* in; const unsigned short* W; const float* bias;
    unsigned short* outp = nullptr; int ch0 = 0;
    float* ssum = nullptr; float* ssq = nullptr;
    if (yb == 0)      { in = xT; W = Wb;             bias = bq;
                        ssum = stat; ssq = stat + 64; ch0 = 0; }
    else if (yb == 1) { in = cT; W = Wb + K_ * CIN_; bias = bk;
                        outp = k_bufh + (size_t)b * K_ * T_; }
    else { int m0 = (yb - 2) * 64; in = cT;
           W = Wb + 2 * K_ * CIN_ + (size_t)m0 * CIN_; bias = bv + m0;
           outp = v_rawh + ((size_t)b * V_ + m0) * T_;
           ssum = stat + 128; ssq = stat + 384; ch0 = m0; }

    const int lane = tid & 63, w = tid >> 6;
    const int col = lane & 15, quad = lane >> 4;
    const int wm = tid >> 2, wp = tid & 3;
    const int xt = tid >> 1, xh = tid & 1;

    f32x4 acc[8];
    #pragma unroll
    for (int j = 0; j < 8; j++) acc[j] = (f32x4){0.f, 0.f, 0.f, 0.f};

    for (int c0 = 0; c0 < CIN_; c0 += 64) {
        {
            const unsigned short* ws = W + (size_t)wm * CIN_ + c0 + wp * 16;
            *(bf16x8*)&Wt[wm][wp * 16]     = *(const bf16x8*)(ws);
            *(bf16x8*)&Wt[wm][wp * 16 + 8] = *(const bf16x8*)(ws + 8);
            const unsigned short* xs = in + ((size_t)b * T_ + t0 + xt) * CIN_ + c0 + xh * 32;
            #pragma unroll
            for (int u = 0; u < 4; u++)
                *(bf16x8*)&Xt[xt][xh * 32 + 8 * u] = *(const bf16x8*)(xs + 8 * u);
        }
        __syncthreads();
        #pragma unroll
        for (int ks = 0; ks < 2; ks++) {
            const int kc = ks * 32 + quad * 8;
            bf16x8 af = *(bf16x8*)&Wt[w * 16 + col][kc];
            #pragma unroll
            for (int j = 0; j < 8; j++) {
                bf16x8 bfr = *(bf16x8*)&Xt[j * 16 + col][kc];
                acc[j] = __builtin_amdgcn_mfma_f32_16x16x32_bf16(af, bfr, acc[j], 0, 0, 0);
            }
        }
        __syncthreads();
    }

    float bias_v[4], s[4], sq[4], mr[4], lr[4];
    #pragma unroll
    for (int r = 0; r < 4; r++) {
        bias_v[r] = bias[w * 16 + quad * 4 + r];
        s[r] = 0.f; sq[r] = 0.f; mr[r] = -1e30f; lr[r] = 0.f;
    }
    #pragma unroll
    for (int j = 0; j < 8; j++) {
        float o[4];
        #pragma unroll
        for (int r = 0; r < 4; r++) {
            o[r] = acc[j][r] + bias_v[r];
            s[r] += o[r]; sq[r] += o[r] * o[r];
        }
        if (yb == 0) {
            ushort4 h;
            h.x = f2bf(o[0]); h.y = f2bf(o[1]); h.z = f2bf(o[2]); h.w = f2bf(o[3]);
            *(ushort4*)(qT + ((size_t)b * T_ + t0 + j * 16 + col) * K_ + w * 16 + quad * 4) = h;
        } else {
            #pragma unroll
            for (int r = 0; r < 4; r++)
                outp[(size_t)(w * 16 + quad * 4 + r) * T_ + t0 + j * 16 + col] = f2bf(o[r]);
            if (yb == 1) {
                #pragma unroll
                for (int r = 0; r < 4; r++) {
                    float mn = fmaxf(mr[r], o[r]);
                    lr[r] = lr[r] * __expf(mr[r] - mn) + __expf(o[r] - mn);
                    mr[r] = mn;
                }
            }
        }
    }
    if (yb == 1) {
        #pragma unroll
        for (int r = 0; r < 4; r++) {
            float m = mr[r], l = lr[r];
            #pragma unroll
            for (int off = 1; off < 16; off <<= 1) {
                float mo = __shfl_xor(m, off, 64);
                float lo = __shfl_xor(l, off, 64);
                float mn = fmaxf(m, mo);
                l = l * __expf(m - mn) + lo * __expf(mo - mn);
                m = mn;
            }
            if (col == 0) {
                int row = w * 16 + quad * 4 + r;
                float* p = kml + (((size_t)b * K_ + row) * 8 + (t0 >> 7)) * 2;
                p[0] = m; p[1] = l;
            }
        }
    } else {
        #pragma unroll
        for (int r = 0; r < 4; r++) {
            float sv = s[r], qv = sq[r];
            #pragma unroll
            for (int off = 1; off < 16; off <<= 1) {
                sv += __shfl_xor(sv, off, 64);
                qv += __shfl_xor(qv, off, 64);
            }
            if (col == 0) {
                int ch = ch0 + w * 16 + quad * 4 + r;
                atomicAdd(&ssum[ch], sv);
                atomicAdd(&ssq[ch], qv);
            }
        }
    }
}

// ---------------------------------------------------------------------------
// lambda6: softmax-normalized lambda partials from bf16 k/v.  512 blocks,
// plain partial stores, NO fences/atomics (R11's counter-tail cost 80 µs in
// device-scope fence serialization — inter-block dataflow stays at kernel
// boundaries).
// ---------------------------------------------------------------------------
__global__ __launch_bounds__(256) void lambda_kernel6(
    const unsigned short* __restrict__ k_bufh, const unsigned short* __restrict__ v_rawh,
    const float* __restrict__ kml, float* __restrict__ clp)
{
    __shared__ __align__(16) float nks[K_][68];
    __shared__ __align__(16) float vls[64][68];
    __shared__ float mrow[64], lrow[64];
    const int tid = threadIdx.x;
    const int b = blockIdx.z, v0 = blockIdx.y * 64, tc = blockIdx.x, t0 = tc * 64;

    if (tid < 64) {
        const float2* p = (const float2*)(kml + ((size_t)b * K_ + tid) * 16);
        float m = -1e30f, l = 0.f;
        #pragma unroll
        for (int sgi = 0; sgi < 8; sgi++) {
            float2 ml = p[sgi];
            float mn = fmaxf(m, ml.x);
            l = l * __expf(m - mn) + ml.y * __expf(ml.x - mn);
            m = mn;
        }
        mrow[tid] = m; lrow[tid] = 1.f / l;
    }
    __syncthreads();
    {
        const int r = tid >> 2, q = tid & 3;
        const unsigned short* nrow = k_bufh + ((size_t)b * K_ + r) * T_ + t0 + q * 16;
        const unsigned short* vrow = v_rawh + ((size_t)b * V_ + v0 + r) * T_ + t0 + q * 16;
        const float mr = mrow[r], li = lrow[r];
        bf16x8 ka = *(const bf16x8*)(nrow);
        bf16x8 kb = *(const bf16x8*)(nrow + 8);
        bf16x8 va = *(const bf16x8*)(vrow);
        bf16x8 vb = *(const bf16x8*)(vrow + 8);
        #pragma unroll
        for (int i = 0; i < 8; i++) {
            nks[r][q * 16 + i]     = __expf(bf2f((unsigned short)ka[i]) - mr) * li;
            nks[r][q * 16 + 8 + i] = __expf(bf2f((unsigned short)kb[i]) - mr) * li;
            vls[q * 16 + i][r]     = bf2f((unsigned short)va[i]);
            vls[q * 16 + 8 + i][r] = bf2f((unsigned short)vb[i]);
        }
    }
    __syncthreads();
    const int tv = tid & 15, tk = tid >> 4;
    float4 acc[4];
    #pragma unroll
    for (int i = 0; i < 4; i++) acc[i] = make_float4(0.f, 0.f, 0.f, 0.f);
    for (int tt = 0; tt < 16; tt++) {
        float4 w0 = *(float4*)&vls[4 * tt + 0][4 * tv];
        float4 w1 = *(float4*)&vls[4 * tt + 1][4 * tv];
        float4 w2 = *(float4*)&vls[4 * tt + 2][4 * tv];
        float4 w3 = *(float4*)&vls[4 * tt + 3][4 * tv];
        #pragma unroll
        for (int i = 0; i < 4; i++) {
            float4 n = *(float4*)&nks[4 * tk + i][4 * tt];
            acc[i] += w0 * n.x + w1 * n.y + w2 * n.z + w3 * n.w;
        }
    }
    #pragma unroll
    for (int i = 0; i < 4; i++)
        *(float4*)&clp[(((size_t)b * NTC_ + tc) * K_ + 4 * tk + i) * V_ + v0 + 4 * tv] = acc[i];
}

// ---------------------------------------------------------------------------
// prep_cl2: sum clp partials; BN params inline from stat.  Separate kernel
// (kernel boundary = the cheap way to get cross-block visibility).
// ---------------------------------------------------------------------------
__global__ __launch_bounds__(256) void prep_cl_kernel2(
    const float* __restrict__ clp, const float* __restrict__ stat,
    const float* __restrict__ gq, const float* __restrict__ betaq,
    const float* __restrict__ gv, const float* __restrict__ betav,
    unsigned short* __restrict__ clb2, float* __restrict__ hterm)
{
    __shared__ float qsc[64], qsh[64], red[4][64];
    const int tid = threadIdx.x;
    const int b = blockIdx.y, v0 = blockIdx.x * 64;
    const float inv_n = 1.f / (B_ * T_);
    if (tid < 64) {
        float mean = stat[tid] * inv_n;
        float var  = stat[64 + tid] * inv_n - mean * mean;
        float sc = gq[tid] * rsqrtf(var + EPS_);
        qsc[tid] = sc; qsh[tid] = betaq[tid] - mean * sc;
    }
    const int vl = tid & 63, kq = tid >> 6;
    const int c = v0 + vl;
    float vmean = stat[128 + c] * inv_n;
    float vvar  = stat[384 + c] * inv_n - vmean * vmean;
    float vsv = gv[c] * rsqrtf(vvar + EPS_);
    float vhv = betav[c] - vmean * vsv;
    __syncthreads();
    float h = 0.f;
    for (int kk = 0; kk < 16; kk++) {
        int k = kq * 16 + kk;
        float a = 0.f;
        #pragma unroll
        for (int tc = 0; tc < NTC_; tc++)
            a += clp[(((size_t)b * NTC_ + tc) * K_ + k) * V_ + c];
        float clbv = a * vsv + vhv;
        h += qsh[k] * clbv;
        clb2[((size_t)b * V_ + c) * K_ + k] = f2bf(clbv * qsc[k]);
    }
    red[kq][vl] = h;
    __syncthreads();
    if (tid < 64)
        hterm[(size_t)b * V_ + v0 + tid] =
            red[0][tid] + red[1][tid] + red[2][tid] + red[3][tid];
}

// ---------------------------------------------------------------------------
// out5: fused qp + content-MFMA + conv epilogue; v window read as bf16.
// ---------------------------------------------------------------------------
__global__ __launch_bounds__(256) void out_kernel5(
    const unsigned short* __restrict__ qT, const unsigned short* __restrict__ clb2,
    const float* __restrict__ hterm, const unsigned short* __restrict__ v_rawh,
    const float* __restrict__ stat,
    const float* __restrict__ gq, const float* __restrict__ betaq,
    const float* __restrict__ gv, const float* __restrict__ betav,
    const float* __restrict__ pos_w, const float* __restrict__ pos_b,
    float* __restrict__ out)
{
    __shared__ unsigned short qTt[64][72];
    __shared__ unsigned short clv[64][72];
    __shared__ float vs2T[88][68];
    __shared__ float qpt[64][24];
    __shared__ float pws[64][24];
    __shared__ float qsc[64], qsh[64];
    __shared__ float consts[24];
    __shared__ float hvs[64];
    const int tid = threadIdx.x;
    const int b = blockIdx.z, v0 = blockIdx.y * 64, t0 = blockIdx.x * 64;
    const float inv_n = 1.f / (B_ * T_);

    if (tid < 64) {
        float mean = stat[tid] * inv_n;
        float var  = stat[64 + tid] * inv_n - mean * mean;
        float sc = gq[tid] * rsqrtf(var + EPS_);
        qsc[tid] = sc; qsh[tid] = betaq[tid] - mean * sc;
        hvs[tid] = hterm[(size_t)b * V_ + v0 + tid];
    }
    {
        const int rl = tid >> 2, part = tid & 3;
        const unsigned short* qs = qT + ((size_t)b * T_ + t0 + rl) * K_ + part * 16;
        *(bf16x8*)&qTt[rl][part * 16]     = *(const bf16x8*)(qs);
        *(bf16x8*)&qTt[rl][part * 16 + 8] = *(const bf16x8*)(qs + 8);
        const unsigned short* cs = clb2 + ((size_t)b * V_ + v0 + rl) * K_ + part * 16;
        *(bf16x8*)&clv[rl][part * 16]     = *(const bf16x8*)(cs);
        *(bf16x8*)&clv[rl][part * 16 + 8] = *(const bf16x8*)(cs + 8);
    }
    {
        const int vl = tid >> 2, qq = tid & 3;
        const int c = v0 + vl;
        float vmean = stat[128 + c] * inv_n;
        float vvar  = stat[384 + c] * inv_n - vmean * vmean;
        float vsv = gv[c] * rsqrtf(vvar + EPS_);
        float vhv = betav[c] - vmean * vsv;
        const unsigned short* vrow = v_rawh + ((size_t)b * V_ + c) * T_;
        #pragma unroll
        for (int i = 0; i < 22; i++) {
            int cc = qq + 4 * i;
            if (cc < 86) {
                int t = t0 + cc - 11;
                vs2T[cc][vl] = (t >= 0 && t < T_) ? bf2f(vrow[t]) * vsv + vhv : 0.f;
            }
        }
    }
    __syncthreads();

    for (int idx = tid; idx < K_ * 24; idx += 256) {
        int k = idx / 24, s = idx % 24;
        pws[k][s] = qsc[k] * (s < KS_ ? pos_w[k * KS_ + s] : pos_b[k]);
    }
    if (tid < 24) {
        float cs = 0.f;
        for (int k = 0; k < K_; k++)
            cs += qsh[k] * (tid < KS_ ? pos_w[k * KS_ + tid] : pos_b[k]);
        consts[tid] = cs;
    }
    __syncthreads();

    {
        const int t = tid >> 2, sg = tid & 3, s0 = sg * 6;
        float a[6];
        #pragma unroll
        for (int u = 0; u < 6; u++) a[u] = consts[s0 + u];
        #pragma unroll
        for (int kb = 0; kb < 8; kb++) {
            bf16x8 qv = *(bf16x8*)&qTt[t][kb * 8];
            #pragma unroll
            for (int j = 0; j < 8; j++) {
                float q = bf2f((unsigned short)qv[j]);
                #pragma unroll
                for (int u = 0; u < 6; u++) a[u] += q * pws[kb * 8 + j][s0 + u];
            }
        }
        #pragma unroll
        for (int u = 0; u < 6; u++) qpt[t][s0 + u] = a[u];
    }
    __syncthreads();

    const int lane = tid & 63, w = tid >> 6;
    const int col = lane & 15, quad = lane >> 4;

    f32x4 acc[4];
    #pragma unroll
    for (int tf = 0; tf < 4; tf++) acc[tf] = (f32x4){0.f, 0.f, 0.f, 0.f};

    #pragma unroll
    for (int ks = 0; ks < 2; ks++) {
        const int kc = ks * 32 + quad * 8;
        bf16x8 af = *(bf16x8*)&clv[w * 16 + col][kc];
        #pragma unroll
        for (int tf = 0; tf < 4; tf++) {
            bf16x8 bq = *(bf16x8*)&qTt[tf * 16 + col][kc];
            acc[tf] = __builtin_amdgcn_mfma_f32_16x16x32_bf16(af, bq, acc[tf], 0, 0, 0);
        }
    }

    const int vb = w * 16 + quad * 4;
    float4 hv4 = *(float4*)&hvs[vb];
    #pragma unroll
    for (int tf = 0; tf < 4; tf++) {
        const int lt = tf * 16 + col;
        float qv[24];
        #pragma unroll
        for (int u = 0; u < 6; u++)
            *(float4*)&qv[4 * u] = *(float4*)&qpt[lt][4 * u];
        float4 a; a.x = acc[tf][0]; a.y = acc[tf][1]; a.z = acc[tf][2]; a.w = acc[tf][3];
        #pragma unroll
        for (int s = 0; s < KS_; s++) {
            float4 wv = *(float4*)&vs2T[lt + s][vb];
            a.x += qv[s] * wv.x; a.y += qv[s] * wv.y;
            a.z += qv[s] * wv.z; a.w += qv[s] * wv.w;
        }
        float base = qv[23];
        a.x += base + hv4.x; a.y += base + hv4.y;
        a.z += base + hv4.z; a.w += base + hv4.w;
        float* ap = (float*)&a;
        #pragma unroll
        for (int r = 0; r < 4; r++)
            out[((size_t)b * V_ + v0 + vb + r) * T_ + t0 + lt] = ap[r];
    }
}

extern "C" void kernel_launch(void* const* d_in, const int* in_sizes, int n_in,
                              void* d_out, int out_size, void* d_ws, size_t ws_size,
                              hipStream_t stream)
{
    const float* x     = (const float*)d_in[0];
    const float* ctx   = (const float*)d_in[1];
    const float* Wq    = (const float*)d_in[2];
    const float* bq    = (const float*)d_in[3];
    const float* Wk    = (const float*)d_in[4];
    const float* bk    = (const float*)d_in[5];
    const float* Wv    = (const float*)d_in[6];
    const float* bv    = (const float*)d_in[7];
    const float* gq    = (const float*)d_in[8];
    const float* betaq = (const float*)d_in[9];
    const float* gv    = (const float*)d_in[10];
    const float* betav = (const float*)d_in[11];
    const float* pos_w = (const float*)d_in[12];
    const float* pos_b = (const float*)d_in[13];
    float* out = (float*)d_out;

    float* ws    = (float*)d_ws;
    float* clp   = ws;                                   // B*NTC*K*V = 2097152 f
    float* stat  = clp + (size_t)B_ * NTC_ * K_ * V_;    // 640
    float* hterm = stat + 640;                           // B*V = 2048
    float* kml   = hterm + (size_t)B_ * V_;              // B*K*16 = 8192
    unsigned short* k_bufh = (unsigned short*)(kml + (size_t)B_ * K_ * 16);  // B*K*T
    unsigned short* v_rawh = k_bufh + (size_t)B_ * K_ * T_;                  // B*V*T
    unsigned short* xT     = v_rawh + (size_t)B_ * V_ * T_;
    unsigned short* cT     = xT + (size_t)B_ * T_ * CIN_;
    unsigned short* Wb     = cT + (size_t)B_ * T_ * CIN_;
    unsigned short* qT     = Wb + (size_t)(2 * K_ + V_) * CIN_;
    unsigned short* clb2   = qT + (size_t)B_ * T_ * K_;

    prep_kernel<<<dim3(2048 + 192), 256, 0, stream>>>(
        x, ctx, Wq, Wk, Wv, xT, cT, Wb, stat);
    proj_mfma5<<<dim3(T_ / 128, 6, B_), 256, 0, stream>>>(
        xT, cT, Wb, bq, bk, bv, k_bufh, v_rawh, qT, stat, kml);
    lambda_kernel6<<<dim3(NTC_, V_ / 64, B_), 256, 0, stream>>>(
        k_bufh, v_rawh, kml, clp);
    prep_cl_kernel2<<<dim3(V_ / 64, B_), 256, 0, stream>>>(
        clp, stat, gq, betaq, gv, betav, clb2, hterm);
    out_kernel5<<<dim3(T_ / 64, V_ / 64, B_), 256, 0, stream>>>(
        qT, clb2, hterm, v_rawh, stat, gq, betaq, gv, betav, pos_w, pos_b, out);
}